// Round 13
// baseline (161.573 us; speedup 1.0000x reference)
//
#include <hip/hip_runtime.h>
#include <hip/hip_bf16.h>

#define H 160
#define W 160
#define HW 25600
#define ROWB 40960      // W * 256 bytes per NHWC row

typedef __attribute__((ext_vector_type(8))) short bf16x8;
typedef __attribute__((ext_vector_type(4))) float f32x4;
typedef __attribute__((ext_vector_type(8))) unsigned short ushort8v;
typedef __attribute__((ext_vector_type(4))) unsigned short ushort4v;

typedef __attribute__((address_space(1))) const unsigned int gu32;
typedef __attribute__((address_space(3))) unsigned int lu32;

__device__ __forceinline__ void gload16(const void* g, void* l) {
    __builtin_amdgcn_global_load_lds((gu32*)g, (lu32*)l, 16, 0, 0);
}

__device__ __forceinline__ unsigned short f2b(float f) {
    unsigned int u = __float_as_uint(f);
    unsigned int r = (u + 0x7fffu + ((u >> 16) & 1u)) >> 16;
    return (unsigned short)r;
}
__device__ __forceinline__ float b2f(unsigned short b) {
    return __uint_as_float(((unsigned int)b) << 16);
}

// ---------------------------------------------------------------------------
// Activation global format (16-B-slot swizzle, key = x&15):
//   pixel p=(y,x): 256 B; 16-B slot for ci-block cb stored at slot cb^(x&15).
// Weight planes (v6): [l][tap][kk][wc][cf][lane64][16B] — the A-fragment for
//   (tap,kk,wc,cf) is a CONTIGUOUS 1 KB; wave loads it coalesced at lane*16.
// d_out scratch: [0,6553600) act X | [6553600,7733248) wbf | [7733248,+4KB) BN
// ws: [0,6553600) act Y | mf 819200 B | params 67600 B   (7,440,400 proven)
// ---------------------------------------------------------------------------

// ===========================================================================
// prep_weights: thread = (l,co,ci) -> 65,536 threads = 256 blocks EXACT.
// ===========================================================================
__global__ __launch_bounds__(256) void prep_weights(
    const float* __restrict__ tw,
    const float* __restrict__ gamma, const float* __restrict__ beta,
    const float* __restrict__ mean,  const float* __restrict__ var,
    char* __restrict__ wbf, float* __restrict__ invshift)
{
    int idx = blockIdx.x * 256 + threadIdx.x;     // 65,536 exact
    int ci = idx & 127;
    int co = (idx >> 7) & 127;
    int l  = idx >> 14;                            // 0..3
    int i15 = co & 15;
    int cf  = (co >> 4) & 3;
    int wc  = co >> 6;
    int kk  = ci >> 5;
    int g   = (ci >> 3) & 3;
    const float* src = tw + ((l * 128 + co) * 128 + ci) * 9;
    char* dst = wbf + l * 294912 + kk * 8192 + wc * 4096 + cf * 1024
                    + (g * 16 + i15) * 16 + (ci & 7) * 2;
#pragma unroll
    for (int t = 0; t < 9; ++t)
        *(unsigned short*)(dst + t * 32768) = f2b(src[t]);

    if (blockIdx.x == 0) {
        for (int c = threadIdx.x; c < 512; c += 256) {
            int ll = c >> 7, ch = c & 127;
            float inv = gamma[ll * 128 + ch] * rsqrtf(var[ll * 128 + ch] + 1e-5f);
            float sh  = beta[ll * 128 + ch] - mean[ll * 128 + ch] * inv;
            invshift[ll * 256 + ch] = inv;
            invshift[ll * 256 + 128 + ch] = sh;
        }
    }
}

// ===========================================================================
// prep_input: cnn batch0 fp32 NCHW -> swizzled NHWC bf16 (act X), key x&15
// ===========================================================================
__global__ __launch_bounds__(256) void prep_input(
    const float* __restrict__ cnn, char* __restrict__ actX)
{
    int idx = blockIdx.x * 256 + threadIdx.x;   // 409,600 exact
    int cb = idx & 15;
    int p  = idx >> 4;
    int x  = p % W;
    int ci0 = cb * 8;
    ushort8v o;
#pragma unroll
    for (int j = 0; j < 8; ++j)
        o[j] = f2b(cnn[(ci0 + j) * HW + p]);
    *(ushort8v*)(actX + p * 256 + ((cb ^ (x & 15)) * 16)) = o;
}

// ===========================================================================
// conv_mfma v6: 3x3 SAME conv 128->128 (+BN+ReLU), A-from-GLOBAL.
// Block 256 thr / 4 waves, tile 128co x 128px (16w x 8h). Grid (10,20)=200.
// Wave (wc,wp) owns 64co x 64px, acc[4][4], full K (no reduction).
// Per tap: 16 coalesced global A-loads (regs) + per-kk 4 ds_read B + 16 MFMA.
// NO barriers in the tap loop; LDS holds only the input tile (46 KB).
// ===========================================================================
template <int PROJ>
__global__ __launch_bounds__(256, 1) void conv_mfma(
    const char* __restrict__ actin,
    const char* __restrict__ wpl,         // 9 x 32768 B (this layer)
    const float* __restrict__ invshift_l, // 256 f32
    char* __restrict__ actout,            // PROJ=0
    const float* __restrict__ pw,         // PROJ=1: (8,128)
    const float* __restrict__ pb,         // (8)
    float* __restrict__ mf)               // (8,HW)
{
    __shared__ __align__(16) char smem[46080];    // IT: [10 rows][18 px][256 B]
    char* IT = smem;

    const int tid  = threadIdx.x;
    const int lane = tid & 63;
    const int w    = tid >> 6;
    const int wc   = w >> 1;         // co half
    const int wp   = w & 1;          // px half (4 rows)
    const int g    = lane >> 4;
    const int i15  = lane & 15;

    const int bx = blockIdx.x;       // 0..9
    const int by = blockIdx.y;       // 0..19
    const int tx0 = bx * 16 - 1;
    const int ty0 = by * 8 - 1;

    // ---- prologue: input tile DMA (clamped addresses, whole waves)
    for (int it = 0; it < 12; ++it) {
        int c = it * 256 + tid;
        if (c < 2880) {                       // 2880 % 64 == 0
            int row  = c / 288;
            int rem  = c - row * 288;
            int px_i = rem >> 4;
            int bo   = (rem & 15) * 16;
            int cy = min(max(ty0 + row, 0), H - 1);
            int cx = min(max(tx0 + px_i, 0), W - 1);
            char* ldsb = IT + (it * 256 + (tid & ~63)) * 16;
            gload16(actin + cy * ROWB + cx * 256 + bo, ldsb);
        }
    }
    asm volatile("s_waitcnt vmcnt(0)" ::: "memory");
    __syncthreads();
    for (int c = tid; c < 2880; c += 256) {   // zero OOB borders
        int row  = c / 288;
        int rem  = c - row * 288;
        int px_i = rem >> 4;
        int gy = ty0 + row, gx = tx0 + px_i;
        if ((unsigned)gy >= (unsigned)H || (unsigned)gx >= (unsigned)W) {
            f32x4 z = {0.f, 0.f, 0.f, 0.f};
            *(f32x4*)(IT + c * 16) = z;
        }
    }
    __syncthreads();

    f32x4 acc[4][4];                 // [cf][pf]
#pragma unroll
    for (int cf = 0; cf < 4; ++cf)
#pragma unroll
        for (int pf = 0; pf < 4; ++pf)
            acc[cf][pf] = (f32x4){0.f, 0.f, 0.f, 0.f};

    const char* wl = wpl + wc * 4096 + lane * 16;   // this wave's A base

#pragma unroll
    for (int tap = 0; tap < 9; ++tap) {
        const int r = tap / 3, s = tap - r * 3;
        const char* wt = wl + tap * 32768;
        bf16x8 A[4][4];              // [kk][cf] — 64 VGPR, coalesced loads
#pragma unroll
        for (int kk = 0; kk < 4; ++kk)
#pragma unroll
            for (int cf = 0; cf < 4; ++cf)
                A[kk][cf] = *(const bf16x8*)(wt + kk * 8192 + cf * 1024);

#pragma unroll
        for (int kk = 0; kk < 4; ++kk) {
            const int slotb = ((kk * 4 + g) ^ ((i15 + s + 15) & 15)) * 16;
            const char* ib = IT + (i15 + s) * 256 + slotb;
            bf16x8 b[4];
#pragma unroll
            for (int pf = 0; pf < 4; ++pf)
                b[pf] = *(const bf16x8*)(ib + (wp * 4 + pf + r) * 4608);
#pragma unroll
            for (int cf = 0; cf < 4; ++cf)
#pragma unroll
                for (int pf = 0; pf < 4; ++pf)
                    acc[cf][pf] = __builtin_amdgcn_mfma_f32_16x16x32_bf16(
                        A[kk][cf], b[pf], acc[cf][pf], 0, 0, 0);
        }
    }

    // ---- epilogue (each wave owns its 64co x 64px; no reduction) ----------
    if (PROJ == 0) {
        const int gx = bx * 16 + i15;    // gx & 15 == i15
#pragma unroll
        for (int cf = 0; cf < 4; ++cf) {
            int co0 = wc * 64 + cf * 16 + g * 4;
            int cb  = wc * 8 + cf * 2 + (g >> 1);
            int sbyte = ((cb ^ i15) * 16) + (g & 1) * 8;
            f32x4 inv4 = *(const f32x4*)&invshift_l[co0];
            f32x4 sh4  = *(const f32x4*)&invshift_l[128 + co0];
#pragma unroll
            for (int pf = 0; pf < 4; ++pf) {
                int gy = by * 8 + wp * 4 + pf;
                f32x4 v = acc[cf][pf];
                ushort4v o;
                o.x = f2b(fmaxf(v.x * inv4.x + sh4.x, 0.f));
                o.y = f2b(fmaxf(v.y * inv4.y + sh4.y, 0.f));
                o.z = f2b(fmaxf(v.z * inv4.z + sh4.z, 0.f));
                o.w = f2b(fmaxf(v.w * inv4.w + sh4.w, 0.f));
                *(ushort4v*)(actout + gy * ROWB + gx * 256 + sbyte) = o;
            }
        }
    } else {
        // fused projection: BN'd layer-4 acts -> actF in LDS, then 8-ch proj
        char* actF = smem;                       // 32 KB [128px][256B]
        float* spw = (float*)(smem + 32768);     // 4 KB
        __syncthreads();                         // all waves done reading IT
#pragma unroll
        for (int cf = 0; cf < 4; ++cf) {
            int co0 = wc * 64 + cf * 16 + g * 4;
            int cb  = wc * 8 + cf * 2 + (g >> 1);
            int sbyte = ((cb ^ i15) * 16) + (g & 1) * 8;
            f32x4 inv4 = *(const f32x4*)&invshift_l[co0];
            f32x4 sh4  = *(const f32x4*)&invshift_l[128 + co0];
#pragma unroll
            for (int pf = 0; pf < 4; ++pf) {
                int px = (wp * 4 + pf) * 16 + i15;   // px & 15 == i15
                f32x4 v = acc[cf][pf];
                ushort4v o;
                o.x = f2b(fmaxf(v.x * inv4.x + sh4.x, 0.f));
                o.y = f2b(fmaxf(v.y * inv4.y + sh4.y, 0.f));
                o.z = f2b(fmaxf(v.z * inv4.z + sh4.z, 0.f));
                o.w = f2b(fmaxf(v.w * inv4.w + sh4.w, 0.f));
                *(ushort4v*)(actF + px * 256 + sbyte) = o;
            }
        }
        for (int i = tid; i < 1024; i += 256) spw[i] = pw[i];
        __syncthreads();
        int pxt = tid >> 1;            // 0..127
        int oh  = (tid & 1) * 4;       // outputs oh..oh+3
        float s0 = 0.f, s1 = 0.f, s2 = 0.f, s3 = 0.f;
#pragma unroll
        for (int cb = 0; cb < 16; ++cb) {
            ushort8v vv = *(const ushort8v*)(actF + pxt * 256 + ((cb ^ (pxt & 15)) * 16));
#pragma unroll
            for (int j = 0; j < 8; ++j) {
                float f = b2f(vv[j]);
                int ci = cb * 8 + j;
                s0 += f * spw[(oh + 0) * 128 + ci];
                s1 += f * spw[(oh + 1) * 128 + ci];
                s2 += f * spw[(oh + 2) * 128 + ci];
                s3 += f * spw[(oh + 3) * 128 + ci];
            }
        }
        int p = (by * 8 + (pxt >> 4)) * W + bx * 16 + (pxt & 15);
        mf[(oh + 0) * HW + p] = s0 + pb[oh + 0];
        mf[(oh + 1) * HW + p] = s1 + pb[oh + 1];
        mf[(oh + 2) * HW + p] = s2 + pb[oh + 2];
        mf[(oh + 3) * HW + p] = s3 + pb[oh + 3];
    }
}

// ===========================================================================
// ctrl: controller conv at the K=100 detection points (fp32)
// ===========================================================================
__global__ __launch_bounds__(256) void ctrl_kernel(
    const float* __restrict__ feat, const float* __restrict__ cw,
    const float* __restrict__ cb, const int* __restrict__ det,
    float* __restrict__ params)
{
    __shared__ float patch[1152];
    const int tid = threadIdx.x;
    const int k = blockIdx.x;
    const int xk = det[2 * k];
    const int yk = det[2 * k + 1];

    for (int i = tid; i < 1152; i += 256) {
        int ci = i / 9;
        int rem = i - ci * 9;
        int r = rem / 3, s = rem - r * 3;
        int gy = yk + r - 1, gx = xk + s - 1;
        float v = 0.f;
        if ((unsigned)gy < (unsigned)H && (unsigned)gx < (unsigned)W)
            v = feat[ci * HW + gy * W + gx];
        patch[i] = v;
    }
    __syncthreads();

    if (tid < 169) {
        float acc = cb[tid];
        const float4* cw4 = (const float4*)&cw[tid * 1152];
        const float4* p4  = (const float4*)patch;
        for (int i = 0; i < 288; ++i) {
            float4 a = p4[i];
            float4 b = cw4[i];
            acc += a.x * b.x + a.y * b.y + a.z * b.z + a.w * b.w;
        }
        params[k * 169 + tid] = acc;
    }
}

// ===========================================================================
// head: 10 detections per block; mf read once, reused 10x.
// ===========================================================================
__global__ __launch_bounds__(256) void head_kernel(
    const float* __restrict__ mf, const float* __restrict__ params,
    const int* __restrict__ det, float* __restrict__ out)
{
    __shared__ float sp[1690];
    __shared__ int sdet[20];
    const int tid = threadIdx.x;
    const int kg = blockIdx.y;
    for (int i = tid; i < 1690; i += 256) sp[i] = params[kg * 1690 + i];
    if (tid < 20) sdet[tid] = det[kg * 20 + tid];
    __syncthreads();

    const int p = blockIdx.x * 256 + tid;
    const int x = p % W;
    const int y = p / W;
    const float fx = (float)(x * 4 + 2);
    const float fy = (float)(y * 4 + 2);

    float f[8];
#pragma unroll
    for (int o = 0; o < 8; ++o) f[o] = mf[o * HW + p];

#pragma unroll 2
    for (int j = 0; j < 10; ++j) {
        const float* spj = &sp[j * 169];
        const float rel0 = (float)(sdet[2 * j] * 4) - fx;
        const float rel1 = (float)(sdet[2 * j + 1] * 4) - fy;
        float h0[8];
#pragma unroll
        for (int o = 0; o < 8; ++o) {
            float a = spj[152 + o] + spj[o * 10] * rel0 + spj[o * 10 + 1] * rel1;
#pragma unroll
            for (int c = 0; c < 8; ++c) a += spj[o * 10 + 2 + c] * f[c];
            h0[o] = fmaxf(a, 0.f);
        }
        float h1[8];
#pragma unroll
        for (int o = 0; o < 8; ++o) {
            float a = spj[160 + o];
#pragma unroll
            for (int c = 0; c < 8; ++c) a += spj[80 + o * 8 + c] * h0[c];
            h1[o] = fmaxf(a, 0.f);
        }
        float r = spj[168];
#pragma unroll
        for (int c = 0; c < 8; ++c) r += spj[144 + c] * h1[c];
        out[(kg * 10 + j) * HW + p] = r;
    }
}

// ===========================================================================
extern "C" void kernel_launch(void* const* d_in, const int* in_sizes, int n_in,
                              void* d_out, int out_size, void* d_ws, size_t ws_size,
                              hipStream_t stream)
{
    const float* cnn    = (const float*)d_in[0];
    const float* towerw = (const float*)d_in[1];
    const float* gamma  = (const float*)d_in[2];
    const float* beta   = (const float*)d_in[3];
    const float* meanp  = (const float*)d_in[4];
    const float* varp   = (const float*)d_in[5];
    const float* projw  = (const float*)d_in[6];
    const float* projb  = (const float*)d_in[7];
    const float* ctrlw  = (const float*)d_in[8];
    const float* ctrlb  = (const float*)d_in[9];
    const int*   det    = (const int*)d_in[10];
    float* out = (float*)d_out;

    char*  outb     = (char*)d_out;
    char*  X        = outb;                          // 6,553,600 B
    char*  wbf      = outb + 6553600;                // 1,179,648 B
    float* invshift = (float*)(outb + 7733248);      // 4,096 B

    char*  Y      = (char*)d_ws;                     // 6,553,600 B
    float* mf     = (float*)((char*)d_ws + 6553600); // 819,200 B
    float* params = (float*)((char*)d_ws + 7372800); // 67,600 B

    const dim3 blk(256);

    prep_weights<<<dim3(256), blk, 0, stream>>>(towerw, gamma, beta, meanp, varp,
                                                wbf, invshift);
    prep_input<<<dim3(1600), blk, 0, stream>>>(cnn, X);

    const dim3 cgrid(10, 20);
    conv_mfma<0><<<cgrid, blk, 0, stream>>>(X, wbf + 0 * 294912, invshift + 0 * 256,
                                            Y, nullptr, nullptr, nullptr);
    conv_mfma<0><<<cgrid, blk, 0, stream>>>(Y, wbf + 1 * 294912, invshift + 1 * 256,
                                            X, nullptr, nullptr, nullptr);
    conv_mfma<0><<<cgrid, blk, 0, stream>>>(X, wbf + 2 * 294912, invshift + 2 * 256,
                                            Y, nullptr, nullptr, nullptr);
    conv_mfma<1><<<cgrid, blk, 0, stream>>>(Y, wbf + 3 * 294912, invshift + 3 * 256,
                                            nullptr, projw, projb, mf);

    ctrl_kernel<<<dim3(100), blk, 0, stream>>>(cnn, ctrlw, ctrlb, det, params);
    head_kernel<<<dim3(100, 10), blk, 0, stream>>>(mf, params, det, out);
}

// Round 14
// 117.947 us; speedup vs baseline: 1.3699x; 1.3699x over previous
//
#include <hip/hip_runtime.h>
#include <hip/hip_bf16.h>

#define H 160
#define W 160
#define HW 25600
#define ROWB 40960      // W * 256 bytes per NHWC row

typedef __attribute__((ext_vector_type(8))) short bf16x8;
typedef __attribute__((ext_vector_type(4))) float f32x4;
typedef __attribute__((ext_vector_type(8))) unsigned short ushort8v;
typedef __attribute__((ext_vector_type(4))) unsigned short ushort4v;

typedef __attribute__((address_space(1))) const unsigned int gu32;
typedef __attribute__((address_space(3))) unsigned int lu32;

__device__ __forceinline__ void gload16(const void* g, void* l) {
    __builtin_amdgcn_global_load_lds((gu32*)g, (lu32*)l, 16, 0, 0);
}

__device__ __forceinline__ unsigned short f2b(float f) {
    unsigned int u = __float_as_uint(f);
    unsigned int r = (u + 0x7fffu + ((u >> 16) & 1u)) >> 16;
    return (unsigned short)r;
}
__device__ __forceinline__ float b2f(unsigned short b) {
    return __uint_as_float(((unsigned int)b) << 16);
}

#define LGKM0() asm volatile("s_waitcnt lgkmcnt(0)" ::: "memory")
#define BARRIER() asm volatile("s_barrier" ::: "memory")

// ---------------------------------------------------------------------------
// Activation global format (16-B-slot swizzle, key = x&15):
//   pixel p=(y,x): 256 B; 16-B slot for ci-block cb stored at slot cb^(x&15).
// Weight planes: [l][tap][kk] 8192 B planes of [co][64 B] (32 ci as bf16).
// d_out scratch: [0,6553600) act X | [6553600,7733248) wbf | [7733248,+4KB) BN
// ws: [0,6553600) act Y | mf 819200 B | params 67600 B   (7,440,400 proven)
// ---------------------------------------------------------------------------

// ===========================================================================
// fused_prep: one kernel, three independent jobs by blockIdx range:
//   [0,100)      ctrl    — controller conv at K=100 detection points
//   [100,1700)   prep_in — cnn batch0 fp32 NCHW -> swizzled NHWC bf16 (X)
//   [1700,1956)  prep_w  — tower weights -> bf16 planes + BN inv/shift
// ===========================================================================
__global__ __launch_bounds__(256) void fused_prep(
    const float* __restrict__ cnn,
    const float* __restrict__ tw,
    const float* __restrict__ gamma, const float* __restrict__ beta,
    const float* __restrict__ mean,  const float* __restrict__ var,
    const float* __restrict__ cw, const float* __restrict__ cb,
    const int*   __restrict__ det,
    char* __restrict__ actX, char* __restrict__ wbf,
    float* __restrict__ invshift, float* __restrict__ params)
{
    const int tid = threadIdx.x;
    const int b = blockIdx.x;

    if (b < 100) {
        // ---------------- ctrl ----------------
        __shared__ float patch[1152];
        const int k = b;
        const int xk = det[2 * k];
        const int yk = det[2 * k + 1];
        for (int i = tid; i < 1152; i += 256) {
            int ci = i / 9;
            int rem = i - ci * 9;
            int r = rem / 3, s = rem - r * 3;
            int gy = yk + r - 1, gx = xk + s - 1;
            float v = 0.f;
            if ((unsigned)gy < (unsigned)H && (unsigned)gx < (unsigned)W)
                v = cnn[ci * HW + gy * W + gx];
            patch[i] = v;
        }
        __syncthreads();
        if (tid < 169) {
            float acc = cb[tid];
            const float4* cw4 = (const float4*)&cw[tid * 1152];
            const float4* p4  = (const float4*)patch;
            for (int i = 0; i < 288; ++i) {
                float4 a = p4[i];
                float4 w = cw4[i];
                acc += a.x * w.x + a.y * w.y + a.z * w.z + a.w * w.w;
            }
            params[k * 169 + tid] = acc;
        }
    } else if (b < 1700) {
        // ---------------- prep_input ----------------
        int idx = (b - 100) * 256 + tid;            // 409,600 exact
        int cb2 = idx & 15;
        int p  = idx >> 4;
        int x  = p % W;
        int ci0 = cb2 * 8;
        ushort8v o;
#pragma unroll
        for (int j = 0; j < 8; ++j)
            o[j] = f2b(cnn[(ci0 + j) * HW + p]);
        *(ushort8v*)(actX + p * 256 + ((cb2 ^ (x & 15)) * 16)) = o;
    } else {
        // ---------------- prep_weights (coalesced, proven R8-R11) ----------
        int idx = (b - 1700) * 256 + tid;           // 65,536 exact
        int ci = idx & 127;
        int co = (idx >> 7) & 127;
        int l  = idx >> 14;                          // 0..3
        int kk = ci >> 5;
        int cw2 = ci & 31;
        const float* src = tw + ((l * 128 + co) * 128 + ci) * 9;
        char* dst = wbf + l * 294912 + kk * 8192 + co * 64 + cw2 * 2;
#pragma unroll
        for (int t = 0; t < 9; ++t)
            *(unsigned short*)(dst + t * 32768) = f2b(src[t]);

        if (b == 1700) {
            for (int c = tid; c < 512; c += 256) {
                int ll = c >> 7, ch = c & 127;
                float inv = gamma[ll * 128 + ch] * rsqrtf(var[ll * 128 + ch] + 1e-5f);
                float sh  = beta[ll * 128 + ch] - mean[ll * 128 + ch] * inv;
                invshift[ll * 256 + ch] = inv;
                invshift[ll * 256 + 128 + ch] = sh;
            }
        }
    }
}

// ===========================================================================
// conv_mfma v7: R6's pipelined CSTAGE x 128px tile.
// Block 256 thr / 4 waves (wc,wp), tile 128co x 128px (16w x 8h). Grid (10,20).
// Per stage (tap,kk): issue plane J+3 -> vmcnt(4) -> 8 ds_read + 16 MFMA ->
// barrier. 36 stages. LDS: IT 46080 B + WQ 4x8192 B = 78848 B.
// PROJ=1: layer-4 output stays in LDS, fused 8-ch projection (v6-proven).
// ===========================================================================
template <int PROJ>
__global__ __launch_bounds__(256, 1) void conv_mfma(
    const char* __restrict__ actin,
    const char* __restrict__ wpl,         // 36 x 8192 B (this layer)
    const float* __restrict__ invshift_l, // 256 f32
    char* __restrict__ actout,            // PROJ=0
    const float* __restrict__ pw,         // PROJ=1: (8,128)
    const float* __restrict__ pb,         // (8)
    float* __restrict__ mf)               // (8,HW)
{
    __shared__ __align__(16) char smem[78848];
    char* IT = smem;                 // 46080 B : [10 rows][18 px][256 B]
    char* WQ = smem + 46080;         // 4 x 8192 B quarter-buffers

    const int tid  = threadIdx.x;
    const int lane = tid & 63;
    const int w    = tid >> 6;
    const int wc   = w >> 1;         // co half (64 co)
    const int wp   = w & 1;          // px half (rows 0-3 / 4-7)
    const int g    = lane >> 4;
    const int i15  = lane & 15;

    const int bx = blockIdx.x;       // 0..9
    const int by = blockIdx.y;       // 0..19
    const int tx0 = bx * 16 - 1;
    const int ty0 = by * 8 - 1;

    // ---- prologue: input tile DMA (clamped) + weight planes 0..2
    for (int it = 0; it < 12; ++it) {
        int c = it * 256 + tid;
        if (c < 2880) {                       // 2880 % 64 == 0: whole waves
            int row  = c / 288;
            int rem  = c - row * 288;
            int px_i = rem >> 4;
            int bo   = (rem & 15) * 16;
            int cy = min(max(ty0 + row, 0), H - 1);
            int cx = min(max(tx0 + px_i, 0), W - 1);
            char* ldsb = IT + (it * 256 + (tid & ~63)) * 16;
            gload16(actin + cy * ROWB + cx * 256 + bo, ldsb);
        }
    }
#pragma unroll
    for (int pl = 0; pl < 3; ++pl) {
        const char* src = wpl + pl * 8192;
        char* dst = WQ + pl * 8192;
        gload16(src + (0 * 256 + tid) * 16, dst + (0 * 256 + (tid & ~63)) * 16);
        gload16(src + (1 * 256 + tid) * 16, dst + (1 * 256 + (tid & ~63)) * 16);
    }
    asm volatile("s_waitcnt vmcnt(6)" ::: "memory");   // all IT landed
    for (int c = tid; c < 2880; c += 256) {            // zero OOB borders
        int row  = c / 288;
        int rem  = c - row * 288;
        int px_i = rem >> 4;
        int gy = ty0 + row, gx = tx0 + px_i;
        if ((unsigned)gy >= (unsigned)H || (unsigned)gx >= (unsigned)W) {
            f32x4 z = {0.f, 0.f, 0.f, 0.f};
            *(f32x4*)(IT + c * 16) = z;
        }
    }
    LGKM0();
    BARRIER();

    f32x4 acc[4][4];                 // [cf][pf] — all indices compile-time
#pragma unroll
    for (int cf = 0; cf < 4; ++cf)
#pragma unroll
        for (int pf = 0; pf < 4; ++pf)
            acc[cf][pf] = (f32x4){0.f, 0.f, 0.f, 0.f};

#define CSTAGE(J, WN) {                                                        \
    if ((J) <= 32) {                                                           \
        const char* src = wpl + ((J) + 3) * 8192;                              \
        char* dst = WQ + (((J) + 3) & 3) * 8192;                               \
        gload16(src + (0*256 + tid) * 16, dst + (0*256 + (tid & ~63)) * 16);   \
        gload16(src + (1*256 + tid) * 16, dst + (1*256 + (tid & ~63)) * 16);   \
    }                                                                          \
    asm volatile("s_waitcnt vmcnt(" #WN ")" ::: "memory");                     \
    {                                                                          \
        const int tap = (J) >> 2, kk = (J) & 3;                                \
        const int r = tap / 3, s = tap - r * 3;                                \
        const char* wbse = WQ + ((J) & 3) * 8192 + (wc * 64 + i15) * 64 + g * 16; \
        bf16x8 a0 = *(const bf16x8*)(wbse + 0 * 1024);                         \
        bf16x8 a1 = *(const bf16x8*)(wbse + 1 * 1024);                         \
        bf16x8 a2 = *(const bf16x8*)(wbse + 2 * 1024);                         \
        bf16x8 a3 = *(const bf16x8*)(wbse + 3 * 1024);                         \
        const int slotb = ((kk * 4 + g) ^ ((i15 + s + 15) & 15)) * 16;         \
        const char* ib = IT + (i15 + s) * 256 + slotb;                         \
        bf16x8 b0 = *(const bf16x8*)(ib + (wp * 4 + 0 + r) * 4608);            \
        bf16x8 b1 = *(const bf16x8*)(ib + (wp * 4 + 1 + r) * 4608);            \
        bf16x8 b2 = *(const bf16x8*)(ib + (wp * 4 + 2 + r) * 4608);            \
        bf16x8 b3 = *(const bf16x8*)(ib + (wp * 4 + 3 + r) * 4608);            \
        acc[0][0] = __builtin_amdgcn_mfma_f32_16x16x32_bf16(a0, b0, acc[0][0], 0, 0, 0); \
        acc[0][1] = __builtin_amdgcn_mfma_f32_16x16x32_bf16(a0, b1, acc[0][1], 0, 0, 0); \
        acc[0][2] = __builtin_amdgcn_mfma_f32_16x16x32_bf16(a0, b2, acc[0][2], 0, 0, 0); \
        acc[0][3] = __builtin_amdgcn_mfma_f32_16x16x32_bf16(a0, b3, acc[0][3], 0, 0, 0); \
        acc[1][0] = __builtin_amdgcn_mfma_f32_16x16x32_bf16(a1, b0, acc[1][0], 0, 0, 0); \
        acc[1][1] = __builtin_amdgcn_mfma_f32_16x16x32_bf16(a1, b1, acc[1][1], 0, 0, 0); \
        acc[1][2] = __builtin_amdgcn_mfma_f32_16x16x32_bf16(a1, b2, acc[1][2], 0, 0, 0); \
        acc[1][3] = __builtin_amdgcn_mfma_f32_16x16x32_bf16(a1, b3, acc[1][3], 0, 0, 0); \
        acc[2][0] = __builtin_amdgcn_mfma_f32_16x16x32_bf16(a2, b0, acc[2][0], 0, 0, 0); \
        acc[2][1] = __builtin_amdgcn_mfma_f32_16x16x32_bf16(a2, b1, acc[2][1], 0, 0, 0); \
        acc[2][2] = __builtin_amdgcn_mfma_f32_16x16x32_bf16(a2, b2, acc[2][2], 0, 0, 0); \
        acc[2][3] = __builtin_amdgcn_mfma_f32_16x16x32_bf16(a2, b3, acc[2][3], 0, 0, 0); \
        acc[3][0] = __builtin_amdgcn_mfma_f32_16x16x32_bf16(a3, b0, acc[3][0], 0, 0, 0); \
        acc[3][1] = __builtin_amdgcn_mfma_f32_16x16x32_bf16(a3, b1, acc[3][1], 0, 0, 0); \
        acc[3][2] = __builtin_amdgcn_mfma_f32_16x16x32_bf16(a3, b2, acc[3][2], 0, 0, 0); \
        acc[3][3] = __builtin_amdgcn_mfma_f32_16x16x32_bf16(a3, b3, acc[3][3], 0, 0, 0); \
    }                                                                          \
    BARRIER();                                                                 \
}

    CSTAGE(0,4)  CSTAGE(1,4)  CSTAGE(2,4)  CSTAGE(3,4)  CSTAGE(4,4)  CSTAGE(5,4)
    CSTAGE(6,4)  CSTAGE(7,4)  CSTAGE(8,4)  CSTAGE(9,4)  CSTAGE(10,4) CSTAGE(11,4)
    CSTAGE(12,4) CSTAGE(13,4) CSTAGE(14,4) CSTAGE(15,4) CSTAGE(16,4) CSTAGE(17,4)
    CSTAGE(18,4) CSTAGE(19,4) CSTAGE(20,4) CSTAGE(21,4) CSTAGE(22,4) CSTAGE(23,4)
    CSTAGE(24,4) CSTAGE(25,4) CSTAGE(26,4) CSTAGE(27,4) CSTAGE(28,4) CSTAGE(29,4)
    CSTAGE(30,4) CSTAGE(31,4) CSTAGE(32,4) CSTAGE(33,2) CSTAGE(34,0) CSTAGE(35,0)
#undef CSTAGE

    // ---- epilogue (v6-proven forms; acc indices compile-time) -------------
    if (PROJ == 0) {
        const int gx = bx * 16 + i15;    // gx & 15 == i15
#pragma unroll
        for (int cf = 0; cf < 4; ++cf) {
            int co0 = wc * 64 + cf * 16 + g * 4;
            int cbx = wc * 8 + cf * 2 + (g >> 1);
            int sbyte = ((cbx ^ i15) * 16) + (g & 1) * 8;
            f32x4 inv4 = *(const f32x4*)&invshift_l[co0];
            f32x4 sh4  = *(const f32x4*)&invshift_l[128 + co0];
#pragma unroll
            for (int pf = 0; pf < 4; ++pf) {
                int gy = by * 8 + wp * 4 + pf;
                f32x4 v = acc[cf][pf];
                ushort4v o;
                o.x = f2b(fmaxf(v.x * inv4.x + sh4.x, 0.f));
                o.y = f2b(fmaxf(v.y * inv4.y + sh4.y, 0.f));
                o.z = f2b(fmaxf(v.z * inv4.z + sh4.z, 0.f));
                o.w = f2b(fmaxf(v.w * inv4.w + sh4.w, 0.f));
                *(ushort4v*)(actout + gy * ROWB + gx * 256 + sbyte) = o;
            }
        }
    } else {
        // fused projection: BN'd layer-4 acts -> actF in LDS, then 8-ch proj
        char* actF = smem;                       // 32 KB [128px][256B]
        float* spw = (float*)(smem + 32768);     // 4 KB
        __syncthreads();                         // everyone done with IT/WQ
#pragma unroll
        for (int cf = 0; cf < 4; ++cf) {
            int co0 = wc * 64 + cf * 16 + g * 4;
            int cbx = wc * 8 + cf * 2 + (g >> 1);
            int sbyte = ((cbx ^ i15) * 16) + (g & 1) * 8;
            f32x4 inv4 = *(const f32x4*)&invshift_l[co0];
            f32x4 sh4  = *(const f32x4*)&invshift_l[128 + co0];
#pragma unroll
            for (int pf = 0; pf < 4; ++pf) {
                int px = (wp * 4 + pf) * 16 + i15;   // px & 15 == i15
                f32x4 v = acc[cf][pf];
                ushort4v o;
                o.x = f2b(fmaxf(v.x * inv4.x + sh4.x, 0.f));
                o.y = f2b(fmaxf(v.y * inv4.y + sh4.y, 0.f));
                o.z = f2b(fmaxf(v.z * inv4.z + sh4.z, 0.f));
                o.w = f2b(fmaxf(v.w * inv4.w + sh4.w, 0.f));
                *(ushort4v*)(actF + px * 256 + sbyte) = o;
            }
        }
        for (int i = tid; i < 1024; i += 256) spw[i] = pw[i];
        __syncthreads();
        int pxt = tid >> 1;            // 0..127
        int oh  = (tid & 1) * 4;       // outputs oh..oh+3
        float s0 = 0.f, s1 = 0.f, s2 = 0.f, s3 = 0.f;
#pragma unroll
        for (int cb2 = 0; cb2 < 16; ++cb2) {
            ushort8v vv = *(const ushort8v*)(actF + pxt * 256 + ((cb2 ^ (pxt & 15)) * 16));
#pragma unroll
            for (int j = 0; j < 8; ++j) {
                float f = b2f(vv[j]);
                int ci = cb2 * 8 + j;
                s0 += f * spw[(oh + 0) * 128 + ci];
                s1 += f * spw[(oh + 1) * 128 + ci];
                s2 += f * spw[(oh + 2) * 128 + ci];
                s3 += f * spw[(oh + 3) * 128 + ci];
            }
        }
        int p = (by * 8 + (pxt >> 4)) * W + bx * 16 + (pxt & 15);
        mf[(oh + 0) * HW + p] = s0 + pb[oh + 0];
        mf[(oh + 1) * HW + p] = s1 + pb[oh + 1];
        mf[(oh + 2) * HW + p] = s2 + pb[oh + 2];
        mf[(oh + 3) * HW + p] = s3 + pb[oh + 3];
    }
}

// ===========================================================================
// head: 10 detections per block; mf read once, reused 10x (proven).
// ===========================================================================
__global__ __launch_bounds__(256) void head_kernel(
    const float* __restrict__ mf, const float* __restrict__ params,
    const int* __restrict__ det, float* __restrict__ out)
{
    __shared__ float sp[1690];
    __shared__ int sdet[20];
    const int tid = threadIdx.x;
    const int kg = blockIdx.y;
    for (int i = tid; i < 1690; i += 256) sp[i] = params[kg * 1690 + i];
    if (tid < 20) sdet[tid] = det[kg * 20 + tid];
    __syncthreads();

    const int p = blockIdx.x * 256 + tid;
    const int x = p % W;
    const int y = p / W;
    const float fx = (float)(x * 4 + 2);
    const float fy = (float)(y * 4 + 2);

    float f[8];
#pragma unroll
    for (int o = 0; o < 8; ++o) f[o] = mf[o * HW + p];

#pragma unroll 2
    for (int j = 0; j < 10; ++j) {
        const float* spj = &sp[j * 169];
        const float rel0 = (float)(sdet[2 * j] * 4) - fx;
        const float rel1 = (float)(sdet[2 * j + 1] * 4) - fy;
        float h0[8];
#pragma unroll
        for (int o = 0; o < 8; ++o) {
            float a = spj[152 + o] + spj[o * 10] * rel0 + spj[o * 10 + 1] * rel1;
#pragma unroll
            for (int c = 0; c < 8; ++c) a += spj[o * 10 + 2 + c] * f[c];
            h0[o] = fmaxf(a, 0.f);
        }
        float h1[8];
#pragma unroll
        for (int o = 0; o < 8; ++o) {
            float a = spj[160 + o];
#pragma unroll
            for (int c = 0; c < 8; ++c) a += spj[80 + o * 8 + c] * h0[c];
            h1[o] = fmaxf(a, 0.f);
        }
        float r = spj[168];
#pragma unroll
        for (int c = 0; c < 8; ++c) r += spj[144 + c] * h1[c];
        out[(kg * 10 + j) * HW + p] = r;
    }
}

// ===========================================================================
extern "C" void kernel_launch(void* const* d_in, const int* in_sizes, int n_in,
                              void* d_out, int out_size, void* d_ws, size_t ws_size,
                              hipStream_t stream)
{
    const float* cnn    = (const float*)d_in[0];
    const float* towerw = (const float*)d_in[1];
    const float* gamma  = (const float*)d_in[2];
    const float* beta   = (const float*)d_in[3];
    const float* meanp  = (const float*)d_in[4];
    const float* varp   = (const float*)d_in[5];
    const float* projw  = (const float*)d_in[6];
    const float* projb  = (const float*)d_in[7];
    const float* ctrlw  = (const float*)d_in[8];
    const float* ctrlb  = (const float*)d_in[9];
    const int*   det    = (const int*)d_in[10];
    float* out = (float*)d_out;

    char*  outb     = (char*)d_out;
    char*  X        = outb;                          // 6,553,600 B
    char*  wbf      = outb + 6553600;                // 1,179,648 B
    float* invshift = (float*)(outb + 7733248);      // 4,096 B

    char*  Y      = (char*)d_ws;                     // 6,553,600 B
    float* mf     = (float*)((char*)d_ws + 6553600); // 819,200 B
    float* params = (float*)((char*)d_ws + 7372800); // 67,600 B

    const dim3 blk(256);

    fused_prep<<<dim3(1956), blk, 0, stream>>>(
        cnn, towerw, gamma, beta, meanp, varp, ctrlw, ctrlb, det,
        X, wbf, invshift, params);

    const dim3 cgrid(10, 20);
    conv_mfma<0><<<cgrid, blk, 0, stream>>>(X, wbf + 0 * 294912, invshift + 0 * 256,
                                            Y, nullptr, nullptr, nullptr);
    conv_mfma<0><<<cgrid, blk, 0, stream>>>(Y, wbf + 1 * 294912, invshift + 1 * 256,
                                            X, nullptr, nullptr, nullptr);
    conv_mfma<0><<<cgrid, blk, 0, stream>>>(X, wbf + 2 * 294912, invshift + 2 * 256,
                                            Y, nullptr, nullptr, nullptr);
    conv_mfma<1><<<cgrid, blk, 0, stream>>>(Y, wbf + 3 * 294912, invshift + 3 * 256,
                                            nullptr, projw, projb, mf);

    head_kernel<<<dim3(100, 10), blk, 0, stream>>>(mf, params, det, out);
}

// Round 15
// 116.668 us; speedup vs baseline: 1.3849x; 1.0110x over previous
//
#include <hip/hip_runtime.h>
#include <hip/hip_bf16.h>

#define H 160
#define W 160
#define HW 25600
#define ROWB 40960      // W * 256 bytes per NHWC row

typedef __attribute__((ext_vector_type(8))) short bf16x8;
typedef __attribute__((ext_vector_type(4))) float f32x4;
typedef __attribute__((ext_vector_type(8))) unsigned short ushort8v;
typedef __attribute__((ext_vector_type(4))) unsigned short ushort4v;

typedef __attribute__((address_space(1))) const unsigned int gu32;
typedef __attribute__((address_space(3))) unsigned int lu32;

__device__ __forceinline__ void gload16(const void* g, void* l) {
    __builtin_amdgcn_global_load_lds((gu32*)g, (lu32*)l, 16, 0, 0);
}

__device__ __forceinline__ unsigned short f2b(float f) {
    unsigned int u = __float_as_uint(f);
    unsigned int r = (u + 0x7fffu + ((u >> 16) & 1u)) >> 16;
    return (unsigned short)r;
}
__device__ __forceinline__ float b2f(unsigned short b) {
    return __uint_as_float(((unsigned int)b) << 16);
}

#define LGKM0() asm volatile("s_waitcnt lgkmcnt(0)" ::: "memory")
#define BARRIER() asm volatile("s_barrier" ::: "memory")

// ---------------------------------------------------------------------------
// Activation global format (16-B-slot swizzle, key = x&15):
//   pixel p=(y,x): 256 B; slot for ci-block cb stored at slot cb^(x&15).
// Weight planes: [l][tap][kk] 8192 B planes of [co][64 B].
// d_out scratch: [0,6553600) act X | [6553600,7733248) wbf | [7733248,+4KB) BN
// ws: [0,6553600) act Y | mf 819200 B | params 67600 B   (7,440,400 proven)
// ---------------------------------------------------------------------------

// ===========================================================================
// fused_prep (blockIdx ranges):
//   [0,100) ctrl | [100,1700) prep_in (coalesced v2) | [1700,1956) prep_w
// ===========================================================================
__global__ __launch_bounds__(256) void fused_prep(
    const float* __restrict__ cnn,
    const float* __restrict__ tw,
    const float* __restrict__ gamma, const float* __restrict__ beta,
    const float* __restrict__ mean,  const float* __restrict__ var,
    const float* __restrict__ cw, const float* __restrict__ cb,
    const int*   __restrict__ det,
    char* __restrict__ actX, char* __restrict__ wbf,
    float* __restrict__ invshift, float* __restrict__ params)
{
    const int tid = threadIdx.x;
    const int b = blockIdx.x;

    if (b < 100) {
        // ---------------- ctrl ----------------
        __shared__ float patch[1152];
        const int k = b;
        const int xk = det[2 * k];
        const int yk = det[2 * k + 1];
        for (int i = tid; i < 1152; i += 256) {
            int ci = i / 9;
            int rem = i - ci * 9;
            int r = rem / 3, s = rem - r * 3;
            int gy = yk + r - 1, gx = xk + s - 1;
            float v = 0.f;
            if ((unsigned)gy < (unsigned)H && (unsigned)gx < (unsigned)W)
                v = cnn[ci * HW + gy * W + gx];
            patch[i] = v;
        }
        __syncthreads();
        if (tid < 169) {
            float acc = cb[tid];
            const float4* cw4 = (const float4*)&cw[tid * 1152];
            const float4* p4  = (const float4*)patch;
            for (int i = 0; i < 288; ++i) {
                float4 a = p4[i];
                float4 w = cw4[i];
                acc += a.x * w.x + a.y * w.y + a.z * w.z + a.w * w.w;
            }
            params[k * 169 + tid] = acc;
        }
    } else if (b < 1700) {
        // ---------------- prep_input (coalesced: wave = 64 consecutive p) ---
        int j = b - 100;                 // 0..1599
        int cb2 = j / 100;               // 0..15
        int p = (j - cb2 * 100) * 256 + tid;    // 0..25599
        int x = p % W;
        int ci0 = cb2 * 8;
        ushort8v o;
#pragma unroll
        for (int jj = 0; jj < 8; ++jj)
            o[jj] = f2b(cnn[(ci0 + jj) * HW + p]);
        *(ushort8v*)(actX + p * 256 + ((cb2 ^ (x & 15)) * 16)) = o;
    } else {
        // ---------------- prep_weights (proven) ----------------------------
        int idx = (b - 1700) * 256 + tid;           // 65,536 exact
        int ci = idx & 127;
        int co = (idx >> 7) & 127;
        int l  = idx >> 14;                          // 0..3
        int kk = ci >> 5;
        int cw2 = ci & 31;
        const float* src = tw + ((l * 128 + co) * 128 + ci) * 9;
        char* dst = wbf + l * 294912 + kk * 8192 + co * 64 + cw2 * 2;
#pragma unroll
        for (int t = 0; t < 9; ++t)
            *(unsigned short*)(dst + t * 32768) = f2b(src[t]);

        if (b == 1700) {
            for (int c = tid; c < 512; c += 256) {
                int ll = c >> 7, ch = c & 127;
                float inv = gamma[ll * 128 + ch] * rsqrtf(var[ll * 128 + ch] + 1e-5f);
                float sh  = beta[ll * 128 + ch] - mean[ll * 128 + ch] * inv;
                invshift[ll * 256 + ch] = inv;
                invshift[ll * 256 + 128 + ch] = sh;
            }
        }
    }
}

// ===========================================================================
// conv_mfma v8: 512 threads / 8 waves, tile 128co x 128px. Grid (10,20).
// Wave (wp=w>>1, wc=w&1) owns 64co x 32px (2 rows): acc[4][2].
// Per stage (tap,kk): issue 1 weight DMA -> vmcnt(2) -> 4 A + 2 B ds_read +
// 8 MFMA -> barrier. 36 stages. 2 waves/SIMD hides LDS/DMA latency.
// vmcnt ladder race-free: prologue vmcnt(2) covers plane 0 for all threads.
// ===========================================================================
template <int PROJ>
__global__ __launch_bounds__(512, 1) void conv_mfma(
    const char* __restrict__ actin,
    const char* __restrict__ wpl,         // 36 x 8192 B (this layer)
    const float* __restrict__ invshift_l, // 256 f32
    char* __restrict__ actout,            // PROJ=0
    const float* __restrict__ pw,         // PROJ=1: (8,128)
    const float* __restrict__ pb,         // (8)
    float* __restrict__ mf)               // (8,HW)
{
    __shared__ __align__(16) char smem[78848];
    char* IT = smem;                 // 46080 B : [10 rows][18 px][256 B]
    char* WQ = smem + 46080;         // 4 x 8192 B quarter-buffers

    const int tid  = threadIdx.x;
    const int lane = tid & 63;
    const int w    = tid >> 6;       // 0..7
    const int wp   = w >> 1;         // 0..3 : rows wp*2, wp*2+1
    const int wc   = w & 1;          // co half (64 co)
    const int g    = lane >> 4;
    const int i15  = lane & 15;

    const int bx = blockIdx.x;       // 0..9
    const int by = blockIdx.y;       // 0..19
    const int tx0 = bx * 16 - 1;
    const int ty0 = by * 8 - 1;

    // ---- prologue: input tile DMA (clamped) + weight planes 0..2
    for (int it = 0; it < 6; ++it) {
        int c = it * 512 + tid;
        if (c < 2880) {                       // 2880 % 64 == 0: whole waves
            int row  = c / 288;
            int rem  = c - row * 288;
            int px_i = rem >> 4;
            int bo   = (rem & 15) * 16;
            int cy = min(max(ty0 + row, 0), H - 1);
            int cx = min(max(tx0 + px_i, 0), W - 1);
            char* ldsb = IT + (it * 512 + (tid & ~63)) * 16;
            gload16(actin + cy * ROWB + cx * 256 + bo, ldsb);
        }
    }
#pragma unroll
    for (int pl = 0; pl < 3; ++pl)
        gload16(wpl + pl * 8192 + tid * 16,
                WQ + pl * 8192 + (tid & ~63) * 16);
    asm volatile("s_waitcnt vmcnt(2)" ::: "memory");   // IT + plane 0 landed
    for (int c = tid; c < 2880; c += 512) {            // zero own OOB chunks
        int row  = c / 288;
        int rem  = c - row * 288;
        int px_i = rem >> 4;
        int gy = ty0 + row, gx = tx0 + px_i;
        if ((unsigned)gy >= (unsigned)H || (unsigned)gx >= (unsigned)W) {
            f32x4 z = {0.f, 0.f, 0.f, 0.f};
            *(f32x4*)(IT + c * 16) = z;
        }
    }
    LGKM0();
    BARRIER();

    f32x4 acc[4][2];                 // [cf][pf] — compile-time indices only
#pragma unroll
    for (int cf = 0; cf < 4; ++cf)
#pragma unroll
        for (int pf = 0; pf < 2; ++pf)
            acc[cf][pf] = (f32x4){0.f, 0.f, 0.f, 0.f};

#define CSTAGE(J, WN) {                                                        \
    if ((J) <= 32)                                                             \
        gload16(wpl + ((J) + 3) * 8192 + tid * 16,                             \
                WQ + (((J) + 3) & 3) * 8192 + (tid & ~63) * 16);               \
    asm volatile("s_waitcnt vmcnt(" #WN ")" ::: "memory");                     \
    {                                                                          \
        const int tap = (J) >> 2, kk = (J) & 3;                                \
        const int r = tap / 3, s = tap - r * 3;                                \
        const char* wbse = WQ + ((J) & 3) * 8192 + (wc * 64 + i15) * 64 + g * 16; \
        bf16x8 a0 = *(const bf16x8*)(wbse + 0 * 1024);                         \
        bf16x8 a1 = *(const bf16x8*)(wbse + 1 * 1024);                         \
        bf16x8 a2 = *(const bf16x8*)(wbse + 2 * 1024);                         \
        bf16x8 a3 = *(const bf16x8*)(wbse + 3 * 1024);                         \
        const int slotb = ((kk * 4 + g) ^ ((i15 + s + 15) & 15)) * 16;         \
        const char* ib = IT + (i15 + s) * 256 + slotb;                         \
        bf16x8 b0 = *(const bf16x8*)(ib + (wp * 2 + 0 + r) * 4608);            \
        bf16x8 b1 = *(const bf16x8*)(ib + (wp * 2 + 1 + r) * 4608);            \
        acc[0][0] = __builtin_amdgcn_mfma_f32_16x16x32_bf16(a0, b0, acc[0][0], 0, 0, 0); \
        acc[0][1] = __builtin_amdgcn_mfma_f32_16x16x32_bf16(a0, b1, acc[0][1], 0, 0, 0); \
        acc[1][0] = __builtin_amdgcn_mfma_f32_16x16x32_bf16(a1, b0, acc[1][0], 0, 0, 0); \
        acc[1][1] = __builtin_amdgcn_mfma_f32_16x16x32_bf16(a1, b1, acc[1][1], 0, 0, 0); \
        acc[2][0] = __builtin_amdgcn_mfma_f32_16x16x32_bf16(a2, b0, acc[2][0], 0, 0, 0); \
        acc[2][1] = __builtin_amdgcn_mfma_f32_16x16x32_bf16(a2, b1, acc[2][1], 0, 0, 0); \
        acc[3][0] = __builtin_amdgcn_mfma_f32_16x16x32_bf16(a3, b0, acc[3][0], 0, 0, 0); \
        acc[3][1] = __builtin_amdgcn_mfma_f32_16x16x32_bf16(a3, b1, acc[3][1], 0, 0, 0); \
    }                                                                          \
    BARRIER();                                                                 \
}

    CSTAGE(0,2)  CSTAGE(1,2)  CSTAGE(2,2)  CSTAGE(3,2)  CSTAGE(4,2)  CSTAGE(5,2)
    CSTAGE(6,2)  CSTAGE(7,2)  CSTAGE(8,2)  CSTAGE(9,2)  CSTAGE(10,2) CSTAGE(11,2)
    CSTAGE(12,2) CSTAGE(13,2) CSTAGE(14,2) CSTAGE(15,2) CSTAGE(16,2) CSTAGE(17,2)
    CSTAGE(18,2) CSTAGE(19,2) CSTAGE(20,2) CSTAGE(21,2) CSTAGE(22,2) CSTAGE(23,2)
    CSTAGE(24,2) CSTAGE(25,2) CSTAGE(26,2) CSTAGE(27,2) CSTAGE(28,2) CSTAGE(29,2)
    CSTAGE(30,2) CSTAGE(31,2) CSTAGE(32,2) CSTAGE(33,1) CSTAGE(34,0) CSTAGE(35,0)
#undef CSTAGE

    // ---- epilogue ---------------------------------------------------------
    if (PROJ == 0) {
        const int gx = bx * 16 + i15;    // gx & 15 == i15
#pragma unroll
        for (int cf = 0; cf < 4; ++cf) {
            int co0 = wc * 64 + cf * 16 + g * 4;
            int cbx = wc * 8 + cf * 2 + (g >> 1);
            int sbyte = ((cbx ^ i15) * 16) + (g & 1) * 8;
            f32x4 inv4 = *(const f32x4*)&invshift_l[co0];
            f32x4 sh4  = *(const f32x4*)&invshift_l[128 + co0];
#pragma unroll
            for (int pf = 0; pf < 2; ++pf) {
                int gy = by * 8 + wp * 2 + pf;
                f32x4 v = acc[cf][pf];
                ushort4v o;
                o.x = f2b(fmaxf(v.x * inv4.x + sh4.x, 0.f));
                o.y = f2b(fmaxf(v.y * inv4.y + sh4.y, 0.f));
                o.z = f2b(fmaxf(v.z * inv4.z + sh4.z, 0.f));
                o.w = f2b(fmaxf(v.w * inv4.w + sh4.w, 0.f));
                *(ushort4v*)(actout + gy * ROWB + gx * 256 + sbyte) = o;
            }
        }
    } else {
        // fused projection: BN'd layer-4 acts -> actF in LDS, then 8-ch proj
        char* actF = smem;                       // 32 KB [128px][256B]
        float* spw = (float*)(smem + 32768);     // 4 KB
        __syncthreads();                         // everyone done with IT/WQ
#pragma unroll
        for (int cf = 0; cf < 4; ++cf) {
            int co0 = wc * 64 + cf * 16 + g * 4;
            int cbx = wc * 8 + cf * 2 + (g >> 1);
            int sbyte = ((cbx ^ i15) * 16) + (g & 1) * 8;
            f32x4 inv4 = *(const f32x4*)&invshift_l[co0];
            f32x4 sh4  = *(const f32x4*)&invshift_l[128 + co0];
#pragma unroll
            for (int pf = 0; pf < 2; ++pf) {
                int px = (wp * 2 + pf) * 16 + i15;   // px & 15 == i15
                f32x4 v = acc[cf][pf];
                ushort4v o;
                o.x = f2b(fmaxf(v.x * inv4.x + sh4.x, 0.f));
                o.y = f2b(fmaxf(v.y * inv4.y + sh4.y, 0.f));
                o.z = f2b(fmaxf(v.z * inv4.z + sh4.z, 0.f));
                o.w = f2b(fmaxf(v.w * inv4.w + sh4.w, 0.f));
                *(ushort4v*)(actF + px * 256 + sbyte) = o;
            }
        }
        for (int i = tid; i < 1024; i += 512) spw[i] = pw[i];
        __syncthreads();
        int pxt = tid >> 2;            // 0..127
        int o0  = (tid & 3) * 2;       // 0,2,4,6
        float s0 = 0.f, s1 = 0.f;
#pragma unroll
        for (int cb2 = 0; cb2 < 16; ++cb2) {
            ushort8v vv = *(const ushort8v*)(actF + pxt * 256 + ((cb2 ^ (pxt & 15)) * 16));
#pragma unroll
            for (int j = 0; j < 8; ++j) {
                float f = b2f(vv[j]);
                int ci = cb2 * 8 + j;
                s0 += f * spw[o0 * 128 + ci];
                s1 += f * spw[(o0 + 1) * 128 + ci];
            }
        }
        int p = (by * 8 + (pxt >> 4)) * W + bx * 16 + (pxt & 15);
        mf[o0 * HW + p]       = s0 + pb[o0];
        mf[(o0 + 1) * HW + p] = s1 + pb[o0 + 1];
    }
}

// ===========================================================================
// head: 10 detections per block; mf read once, reused 10x (proven).
// ===========================================================================
__global__ __launch_bounds__(256) void head_kernel(
    const float* __restrict__ mf, const float* __restrict__ params,
    const int* __restrict__ det, float* __restrict__ out)
{
    __shared__ float sp[1690];
    __shared__ int sdet[20];
    const int tid = threadIdx.x;
    const int kg = blockIdx.y;
    for (int i = tid; i < 1690; i += 256) sp[i] = params[kg * 1690 + i];
    if (tid < 20) sdet[tid] = det[kg * 20 + tid];
    __syncthreads();

    const int p = blockIdx.x * 256 + tid;
    const int x = p % W;
    const int y = p / W;
    const float fx = (float)(x * 4 + 2);
    const float fy = (float)(y * 4 + 2);

    float f[8];
#pragma unroll
    for (int o = 0; o < 8; ++o) f[o] = mf[o * HW + p];

#pragma unroll 2
    for (int j = 0; j < 10; ++j) {
        const float* spj = &sp[j * 169];
        const float rel0 = (float)(sdet[2 * j] * 4) - fx;
        const float rel1 = (float)(sdet[2 * j + 1] * 4) - fy;
        float h0[8];
#pragma unroll
        for (int o = 0; o < 8; ++o) {
            float a = spj[152 + o] + spj[o * 10] * rel0 + spj[o * 10 + 1] * rel1;
#pragma unroll
            for (int c = 0; c < 8; ++c) a += spj[o * 10 + 2 + c] * f[c];
            h0[o] = fmaxf(a, 0.f);
        }
        float h1[8];
#pragma unroll
        for (int o = 0; o < 8; ++o) {
            float a = spj[160 + o];
#pragma unroll
            for (int c = 0; c < 8; ++c) a += spj[80 + o * 8 + c] * h0[c];
            h1[o] = fmaxf(a, 0.f);
        }
        float r = spj[168];
#pragma unroll
        for (int c = 0; c < 8; ++c) r += spj[144 + c] * h1[c];
        out[(kg * 10 + j) * HW + p] = r;
    }
}

// ===========================================================================
extern "C" void kernel_launch(void* const* d_in, const int* in_sizes, int n_in,
                              void* d_out, int out_size, void* d_ws, size_t ws_size,
                              hipStream_t stream)
{
    const float* cnn    = (const float*)d_in[0];
    const float* towerw = (const float*)d_in[1];
    const float* gamma  = (const float*)d_in[2];
    const float* beta   = (const float*)d_in[3];
    const float* meanp  = (const float*)d_in[4];
    const float* varp   = (const float*)d_in[5];
    const float* projw  = (const float*)d_in[6];
    const float* projb  = (const float*)d_in[7];
    const float* ctrlw  = (const float*)d_in[8];
    const float* ctrlb  = (const float*)d_in[9];
    const int*   det    = (const int*)d_in[10];
    float* out = (float*)d_out;

    char*  outb     = (char*)d_out;
    char*  X        = outb;                          // 6,553,600 B
    char*  wbf      = outb + 6553600;                // 1,179,648 B
    float* invshift = (float*)(outb + 7733248);      // 4,096 B

    char*  Y      = (char*)d_ws;                     // 6,553,600 B
    float* mf     = (float*)((char*)d_ws + 6553600); // 819,200 B
    float* params = (float*)((char*)d_ws + 7372800); // 67,600 B

    fused_prep<<<dim3(1956), dim3(256), 0, stream>>>(
        cnn, towerw, gamma, beta, meanp, varp, ctrlw, ctrlb, det,
        X, wbf, invshift, params);

    const dim3 cgrid(10, 20);
    conv_mfma<0><<<cgrid, dim3(512), 0, stream>>>(X, wbf + 0 * 294912, invshift + 0 * 256,
                                                  Y, nullptr, nullptr, nullptr);
    conv_mfma<0><<<cgrid, dim3(512), 0, stream>>>(Y, wbf + 1 * 294912, invshift + 1 * 256,
                                                  X, nullptr, nullptr, nullptr);
    conv_mfma<0><<<cgrid, dim3(512), 0, stream>>>(X, wbf + 2 * 294912, invshift + 2 * 256,
                                                  Y, nullptr, nullptr, nullptr);
    conv_mfma<1><<<cgrid, dim3(512), 0, stream>>>(Y, wbf + 3 * 294912, invshift + 3 * 256,
                                                  nullptr, projw, projb, mf);

    head_kernel<<<dim3(100, 10), dim3(256), 0, stream>>>(mf, params, det, out);
}